// Round 1
// baseline (755.088 us; speedup 1.0000x reference)
//
#include <hip/hip_runtime.h>
#include <cstdint>
#include <cstddef>

#define NNODES 100000
#define NEDGES 1600000
#define INCH   128
#define HID    128
#define NCLS   40
#define NCOMM_ 1000

static __device__ __forceinline__ float4 ld4(const float* p){ return *reinterpret_cast<const float4*>(p); }

// ---------------- counting (degrees by dst, community sizes) ----------------
__global__ void k_count(const int* __restrict__ ei, int* __restrict__ deg,
                        const int* __restrict__ comm, int* __restrict__ ccnt){
  int idx = blockIdx.x*blockDim.x + threadIdx.x;
  if (idx < NEDGES) atomicAdd(&deg[ei[NEDGES + idx]], 1);
  if (idx < NNODES) atomicAdd(&ccnt[comm[idx]], 1);
}

// ---------------- generic 3-phase exclusive scan (int) ----------------
__global__ void k_scan1(const int* __restrict__ in, int n, int* __restrict__ part){
  int t=threadIdx.x, b=blockIdx.x;
  int base=b*1024+t*4, s=0;
  #pragma unroll
  for(int j=0;j<4;j++){ int i=base+j; if(i<n) s+=in[i]; }
  #pragma unroll
  for(int off=32;off>0;off>>=1) s+=__shfl_down(s,off,64);
  __shared__ int wm[4];
  if((t&63)==0) wm[t>>6]=s;
  __syncthreads();
  if(t==0) part[b]=wm[0]+wm[1]+wm[2]+wm[3];
}

__global__ void k_scan2(int* __restrict__ part, int P){
  __shared__ int sm[256];
  int t=threadIdx.x;
  int v=(t<P)?part[t]:0;
  sm[t]=v; __syncthreads();
  #pragma unroll
  for(int off=1;off<256;off<<=1){
    int u=(t>=off)?sm[t-off]:0;
    __syncthreads();
    sm[t]+=u;
    __syncthreads();
  }
  if(t<P) part[t]=(t==0)?0:sm[t-1];
  if(t==0) part[P]=sm[255];
}

__global__ void k_scan3(const int* __restrict__ in, int n, const int* __restrict__ part, int P,
                        int* __restrict__ out){
  int t=threadIdx.x,b=blockIdx.x;
  int base=b*1024+t*4;
  int v[4], ts=0;
  #pragma unroll
  for(int j=0;j<4;j++){ v[j]=(base+j<n)?in[base+j]:0; ts+=v[j]; }
  int lane=t&63, w=t>>6, sc=ts;
  #pragma unroll
  for(int off=1;off<64;off<<=1){ int u=__shfl_up(sc,off,64); if(lane>=off) sc+=u; }
  __shared__ int wm[4];
  if(lane==63) wm[w]=sc;
  __syncthreads();
  int woff=0;
  for(int i=0;i<w;i++) woff+=wm[i];
  int pos=part[b]+woff+sc-ts;
  #pragma unroll
  for(int j=0;j<4;j++){ if(base+j<n) out[base+j]=pos; pos+=v[j]; }
  if(b==0 && t==0) out[n]=part[P];
}

// ---------------- per-node norm factors ----------------
__global__ void k_nodeprep(const int* __restrict__ deg, float* __restrict__ dis, float* __restrict__ dinv){
  int i=blockIdx.x*blockDim.x+threadIdx.x;
  if(i<NNODES){ float d=(float)(deg[i]+1); dis[i]=rsqrtf(d); dinv[i]=1.0f/d; }
}

// ---------------- CSR fills ----------------
__global__ void k_fill_edges(const int* __restrict__ ei, const int* __restrict__ rp, int* __restrict__ fill,
                             const float* __restrict__ dis, int* __restrict__ col, float* __restrict__ wn){
  int e=blockIdx.x*blockDim.x+threadIdx.x;
  if(e<NEDGES){
    int s=ei[e], d=ei[NEDGES+e];
    int p=rp[d]+atomicAdd(&fill[d],1);
    col[p]=s;
    wn[p]=dis[s];
  }
}

__global__ void k_fill_comm(const int* __restrict__ comm, const int* __restrict__ crow, int* __restrict__ cfill,
                            int* __restrict__ cnode){
  int i=blockIdx.x*blockDim.x+threadIdx.x;
  if(i<NNODES){
    int c=comm[i];
    int p=crow[c]+atomicAdd(&cfill[c],1);
    cnode[p]=i;
  }
}

// ---------------- community mean ----------------
__global__ void k_comm_mean(const float* __restrict__ x, const int* __restrict__ crow,
                            const int* __restrict__ cnode, float* __restrict__ cmean){
  int c=blockIdx.x; int f=threadIdx.x; // 128 threads
  int a=crow[c], b=crow[c+1];
  float s=0.f;
  for(int j=a;j<b;j++){
    int nd=cnode[j];
    s += x[(size_t)nd*INCH + f];
  }
  float cnt=(float)(b-a);
  cmean[(size_t)c*INCH + f] = s / fmaxf(cnt,1.0f);
}

// ---------------- f32 GEMM, BN=128 output cols ----------------
// C[M][128] = A[M][K] * W[K][128] (+bias)(+relu). CONCAT: A = [x | cmean[comm]]
template<int K, bool CONCAT, bool BIAS, bool RELU>
__global__ __launch_bounds__(256) void k_gemm128(const float* __restrict__ A0, const float* __restrict__ A1,
                                                 const int* __restrict__ comm,
                                                 const float* __restrict__ W, const float* __restrict__ bias,
                                                 float* __restrict__ out, int M){
  constexpr int KC=32;
  __shared__ float As[KC][128+4];   // transposed: As[kk][row]
  __shared__ float Ws[KC][128];
  int t=threadIdx.x;
  int m0=blockIdx.x*128;
  int tr=t>>4, tc=t&15;
  float acc[8][8];
  #pragma unroll
  for(int i=0;i<8;i++)
    #pragma unroll
    for(int j=0;j<8;j++) acc[i][j]=0.f;

  for(int kc=0;kc<K;kc+=KC){
    __syncthreads();
    // stage A chunk (transposed)
    {
      int arow=t>>3; int ac4=(t&7)*4;
      #pragma unroll
      for(int p=0;p<4;p++){
        int row=arow+32*p; int gr=m0+row;
        float4 v={0.f,0.f,0.f,0.f};
        if(gr<M){
          const float* src;
          if(CONCAT){
            if(kc<128) src=&A0[(size_t)gr*128 + kc + ac4];
            else { int cm=comm[gr]; src=&A1[(size_t)cm*128 + (kc-128) + ac4]; }
          } else {
            src=&A0[(size_t)gr*K + kc + ac4];
          }
          v=ld4(src);
        }
        As[ac4+0][row]=v.x; As[ac4+1][row]=v.y; As[ac4+2][row]=v.z; As[ac4+3][row]=v.w;
      }
      int wr=t>>5; int wc4=(t&31)*4;
      #pragma unroll
      for(int p=0;p<4;p++){
        int krow=wr+8*p;
        float4 v=ld4(&W[(size_t)(kc+krow)*128 + wc4]);
        *reinterpret_cast<float4*>(&Ws[krow][wc4])=v;
      }
    }
    __syncthreads();
    #pragma unroll 8
    for(int kk=0;kk<KC;kk++){
      float a[8], w[8];
      *reinterpret_cast<float4*>(&a[0])=*reinterpret_cast<const float4*>(&As[kk][tr*8]);
      *reinterpret_cast<float4*>(&a[4])=*reinterpret_cast<const float4*>(&As[kk][tr*8+4]);
      *reinterpret_cast<float4*>(&w[0])=*reinterpret_cast<const float4*>(&Ws[kk][tc*8]);
      *reinterpret_cast<float4*>(&w[4])=*reinterpret_cast<const float4*>(&Ws[kk][tc*8+4]);
      #pragma unroll
      for(int i=0;i<8;i++)
        #pragma unroll
        for(int j=0;j<8;j++) acc[i][j]=fmaf(a[i],w[j],acc[i][j]);
    }
  }

  float bv[8];
  #pragma unroll
  for(int j=0;j<8;j++) bv[j] = BIAS ? bias[tc*8+j] : 0.f;
  #pragma unroll
  for(int i=0;i<8;i++){
    int gr=m0+tr*8+i;
    if(gr<M){
      float o[8];
      #pragma unroll
      for(int j=0;j<8;j++){
        float v=acc[i][j]+bv[j];
        o[j]= RELU ? fmaxf(v,0.f) : v;
      }
      *reinterpret_cast<float4*>(&out[(size_t)gr*128+tc*8  ])=*reinterpret_cast<float4*>(&o[0]);
      *reinterpret_cast<float4*>(&out[(size_t)gr*128+tc*8+4])=*reinterpret_cast<float4*>(&o[4]);
    }
  }
}

// ---------------- f32 GEMM, K=128 -> 40 output cols (no bias/relu) ----------------
__global__ __launch_bounds__(256) void k_gemm40(const float* __restrict__ A, const float* __restrict__ W,
                                                float* __restrict__ out, int M){
  constexpr int KC=32, BM=256;
  __shared__ float As[KC][BM+4];
  __shared__ float Ws[128][40];
  int t=threadIdx.x; int m0=blockIdx.x*BM;
  #pragma unroll
  for(int p=0;p<20;p++){ int i=t+256*p; Ws[i/40][i%40]=W[i]; }  // 5120 elems
  float acc[4][10];
  #pragma unroll
  for(int i=0;i<4;i++)
    #pragma unroll
    for(int j=0;j<10;j++) acc[i][j]=0.f;
  int rg=t>>2, cg=t&3;
  for(int kc=0;kc<128;kc+=KC){
    __syncthreads();
    #pragma unroll
    for(int p=0;p<8;p++){
      int fi=t+256*p; int row=fi>>3; int c4=(fi&7)*4; int gr=m0+row;
      float4 v={0.f,0.f,0.f,0.f};
      if(gr<M) v=ld4(&A[(size_t)gr*128+kc+c4]);
      As[c4+0][row]=v.x; As[c4+1][row]=v.y; As[c4+2][row]=v.z; As[c4+3][row]=v.w;
    }
    __syncthreads();
    #pragma unroll 8
    for(int kk=0;kk<KC;kk++){
      float a[4];
      *reinterpret_cast<float4*>(&a[0])=*reinterpret_cast<const float4*>(&As[kk][rg*4]);
      float w[10];
      #pragma unroll
      for(int q=0;q<5;q++){
        *reinterpret_cast<float2*>(&w[2*q])=*reinterpret_cast<const float2*>(&Ws[kc+kk][cg*10+2*q]);
      }
      #pragma unroll
      for(int i=0;i<4;i++)
        #pragma unroll
        for(int j=0;j<10;j++) acc[i][j]=fmaf(a[i],w[j],acc[i][j]);
    }
  }
  #pragma unroll
  for(int i=0;i<4;i++){
    int gr=m0+rg*4+i;
    if(gr<M){
      #pragma unroll
      for(int q=0;q<5;q++){
        float2 v; v.x=acc[i][2*q]; v.y=acc[i][2*q+1];
        *reinterpret_cast<float2*>(&out[(size_t)gr*40+cg*10+2*q])=v;
      }
    }
  }
}

// ---------------- aggregation layer1 (128 feats): h1 = relu(agg + hw*dinv + b1) ----------------
__global__ __launch_bounds__(64) void k_agg_h(const float* __restrict__ hw, const int* __restrict__ rp,
                                              const int* __restrict__ col, const float* __restrict__ wn,
                                              const float* __restrict__ dis, const float* __restrict__ dinv,
                                              const float* __restrict__ bias, float* __restrict__ out){
  int i=blockIdx.x; int l=threadIdx.x;
  int e0=rp[i], e1=rp[i+1];
  float di=dis[i];
  float ax=0.f, ay=0.f;
  for(int e=e0;e<e1;e++){
    int s=col[e];
    float nr=di*wn[e];
    float2 v=*reinterpret_cast<const float2*>(&hw[(size_t)s*128+2*l]);
    ax=fmaf(v.x,nr,ax); ay=fmaf(v.y,nr,ay);
  }
  float2 sv=*reinterpret_cast<const float2*>(&hw[(size_t)i*128+2*l]);
  float dv=dinv[i];
  float2 bb=*reinterpret_cast<const float2*>(&bias[2*l]);
  float2 o;
  o.x=fmaxf(fmaf(sv.x,dv,ax)+bb.x,0.f);
  o.y=fmaxf(fmaf(sv.y,dv,ay)+bb.y,0.f);
  *reinterpret_cast<float2*>(&out[(size_t)i*128+2*l])=o;
}

// ---------------- aggregation layer2 (40 feats): out = agg + hw2*dinv + b2 ----------------
__global__ __launch_bounds__(64) void k_agg_out(const float* __restrict__ hw2, const int* __restrict__ rp,
                                                const int* __restrict__ col, const float* __restrict__ wn,
                                                const float* __restrict__ dis, const float* __restrict__ dinv,
                                                const float* __restrict__ bias, float* __restrict__ out){
  int i=blockIdx.x; int l=threadIdx.x;
  if(l>=NCLS) return;
  int e0=rp[i], e1=rp[i+1];
  float di=dis[i];
  float a=0.f;
  for(int e=e0;e<e1;e++){
    int s=col[e];
    float nr=di*wn[e];
    a=fmaf(hw2[(size_t)s*NCLS+l],nr,a);
  }
  out[(size_t)i*NCLS+l]= a + hw2[(size_t)i*NCLS+l]*dinv[i] + bias[l];
}

// ---------------- launcher ----------------
extern "C" void kernel_launch(void* const* d_in, const int* in_sizes, int n_in,
                              void* d_out, int out_size, void* d_ws, size_t ws_size,
                              hipStream_t stream) {
  const float* x    = (const float*)d_in[0];
  const int*   ei   = (const int*)  d_in[1];
  const int*   comm = (const int*)  d_in[2];
  const float* W_in = (const float*)d_in[3];
  const float* b_in = (const float*)d_in[4];
  const float* W1   = (const float*)d_in[5];
  const float* b1   = (const float*)d_in[6];
  const float* W2   = (const float*)d_in[7];
  const float* b2   = (const float*)d_in[8];
  float* out = (float*)d_out;

  char* base=(char*)d_ws; size_t off=0;
  auto alloc=[&](size_t bytes)->void*{ void* p=base+off; off=(off+bytes+255)&~(size_t)255; return p; };

  // zero zone (single contiguous memset): deg, fill, ccnt, cfill
  int* zz    =(int*)alloc((size_t)(2*NNODES+2*NCOMM_)*4);
  int* deg_i = zz;
  int* fill  = zz + NNODES;
  int* ccnt  = zz + 2*NNODES;
  int* cfill = zz + 2*NNODES + NCOMM_;
  int* rp    =(int*)alloc((size_t)(NNODES+1)*4);
  int* crow  =(int*)alloc((size_t)(NCOMM_+1)*4);
  int* partA =(int*)alloc(260*4);
  int* partB =(int*)alloc(16*4);
  int* col   =(int*)alloc((size_t)NEDGES*4);
  float* wn  =(float*)alloc((size_t)NEDGES*4);
  int* cnode =(int*)alloc((size_t)NNODES*4);
  float* dis =(float*)alloc((size_t)NNODES*4);
  float* dinv=(float*)alloc((size_t)NNODES*4);
  float* cmean=(float*)alloc((size_t)NCOMM_*INCH*4);
  float* h0  =(float*)alloc((size_t)NNODES*HID*4);   // reused as h1
  float* hw  =(float*)alloc((size_t)NNODES*HID*4);   // reused as hw2

  hipMemsetAsync(zz, 0, (size_t)(2*NNODES+2*NCOMM_)*4, stream);

  int gE=(NEDGES+255)/256, gN=(NNODES+255)/256;
  k_count<<<gE,256,0,stream>>>(ei, deg_i, comm, ccnt);

  int PA=(NNODES+1023)/1024;   // 98
  k_scan1<<<PA,256,0,stream>>>(deg_i, NNODES, partA);
  k_scan2<<<1,256,0,stream>>>(partA, PA);
  k_scan3<<<PA,256,0,stream>>>(deg_i, NNODES, partA, PA, rp);

  int PB=(NCOMM_+1023)/1024;   // 1
  k_scan1<<<PB,256,0,stream>>>(ccnt, NCOMM_, partB);
  k_scan2<<<1,256,0,stream>>>(partB, PB);
  k_scan3<<<PB,256,0,stream>>>(ccnt, NCOMM_, partB, PB, crow);

  k_nodeprep<<<gN,256,0,stream>>>(deg_i, dis, dinv);
  k_fill_edges<<<gE,256,0,stream>>>(ei, rp, fill, dis, col, wn);
  k_fill_comm<<<gN,256,0,stream>>>(comm, crow, cfill, cnode);
  k_comm_mean<<<NCOMM_,128,0,stream>>>(x, crow, cnode, cmean);

  int gM=(NNODES+127)/128;
  // h0 = relu([x | cmean[comm]] @ W_in + b_in)
  k_gemm128<256,true,true,true><<<gM,256,0,stream>>>(x, cmean, comm, W_in, b_in, h0, NNODES);
  // hw = h0 @ W1
  k_gemm128<128,false,false,false><<<gM,256,0,stream>>>(h0, nullptr, nullptr, W1, nullptr, hw, NNODES);
  // h1 (into h0 buffer) = relu(agg(hw) + hw*dinv + b1)
  k_agg_h<<<NNODES,64,0,stream>>>(hw, rp, col, wn, dis, dinv, b1, h0);
  // hw2 (into hw buffer) = h1 @ W2
  k_gemm40<<<(NNODES+255)/256,256,0,stream>>>(h0, W2, hw, NNODES);
  // out = agg(hw2) + hw2*dinv + b2
  k_agg_out<<<NNODES,64,0,stream>>>(hw, rp, col, wn, dis, dinv, b2, out);
}

// Round 2
// 610.123 us; speedup vs baseline: 1.2376x; 1.2376x over previous
//
#include <hip/hip_runtime.h>
#include <cstdint>
#include <cstddef>

#define NNODES 100000
#define NEDGES 1600000
#define INCH   128
#define HID    128
#define NCLS   40
#define NCOMM_ 1000

typedef unsigned int uint32;
typedef unsigned short ushort16;
typedef short s16x8 __attribute__((ext_vector_type(8)));
typedef float f32x4 __attribute__((ext_vector_type(4)));

static __device__ __forceinline__ float4 ld4(const float* p){ return *reinterpret_cast<const float4*>(p); }

// f32 -> bf16 (RTN-even) and back, via bit ops
static __device__ __forceinline__ unsigned short f2b(float f){
  union{float f; uint32 u;} v; v.f=f;
  uint32 r = v.u + 0x7fffu + ((v.u>>16)&1u);
  return (unsigned short)(r>>16);
}
static __device__ __forceinline__ float b2f(unsigned short h){
  union{uint32 u; float f;} v; v.u = ((uint32)h)<<16; return v.f;
}

// ---------------- counting (degrees by dst, community sizes) ----------------
__global__ void k_count(const int* __restrict__ ei, int* __restrict__ deg,
                        const int* __restrict__ comm, int* __restrict__ ccnt){
  int idx = blockIdx.x*blockDim.x + threadIdx.x;
  if (idx < NEDGES) atomicAdd(&deg[ei[NEDGES + idx]], 1);
  if (idx < NNODES) atomicAdd(&ccnt[comm[idx]], 1);
}

// ---------------- generic 3-phase exclusive scan (int) ----------------
__global__ void k_scan1(const int* __restrict__ in, int n, int* __restrict__ part){
  int t=threadIdx.x, b=blockIdx.x;
  int base=b*1024+t*4, s=0;
  #pragma unroll
  for(int j=0;j<4;j++){ int i=base+j; if(i<n) s+=in[i]; }
  #pragma unroll
  for(int off=32;off>0;off>>=1) s+=__shfl_down(s,off,64);
  __shared__ int wm[4];
  if((t&63)==0) wm[t>>6]=s;
  __syncthreads();
  if(t==0) part[b]=wm[0]+wm[1]+wm[2]+wm[3];
}

__global__ void k_scan2(int* __restrict__ part, int P){
  __shared__ int sm[256];
  int t=threadIdx.x;
  int v=(t<P)?part[t]:0;
  sm[t]=v; __syncthreads();
  #pragma unroll
  for(int off=1;off<256;off<<=1){
    int u=(t>=off)?sm[t-off]:0;
    __syncthreads();
    sm[t]+=u;
    __syncthreads();
  }
  if(t<P) part[t]=(t==0)?0:sm[t-1];
  if(t==0) part[P]=sm[255];
}

__global__ void k_scan3(const int* __restrict__ in, int n, const int* __restrict__ part, int P,
                        int* __restrict__ out){
  int t=threadIdx.x,b=blockIdx.x;
  int base=b*1024+t*4;
  int v[4], ts=0;
  #pragma unroll
  for(int j=0;j<4;j++){ v[j]=(base+j<n)?in[base+j]:0; ts+=v[j]; }
  int lane=t&63, w=t>>6, sc=ts;
  #pragma unroll
  for(int off=1;off<64;off<<=1){ int u=__shfl_up(sc,off,64); if(lane>=off) sc+=u; }
  __shared__ int wm[4];
  if(lane==63) wm[w]=sc;
  __syncthreads();
  int woff=0;
  for(int i=0;i<w;i++) woff+=wm[i];
  int pos=part[b]+woff+sc-ts;
  #pragma unroll
  for(int j=0;j<4;j++){ if(base+j<n) out[base+j]=pos; pos+=v[j]; }
  if(b==0 && t==0) out[n]=part[P];
}

// ---------------- per-node norm factors ----------------
__global__ void k_nodeprep(const int* __restrict__ deg, float* __restrict__ dis, float* __restrict__ dinv){
  int i=blockIdx.x*blockDim.x+threadIdx.x;
  if(i<NNODES){ float d=(float)(deg[i]+1); dis[i]=rsqrtf(d); dinv[i]=1.0f/d; }
}

// ---------------- CSR fills: packed edge record {src, dis[src]} ----------------
__global__ void k_fill_edges(const int* __restrict__ ei, const int* __restrict__ rp, int* __restrict__ fill,
                             const float* __restrict__ dis, int2* __restrict__ ep){
  int e=blockIdx.x*blockDim.x+threadIdx.x;
  if(e<NEDGES){
    int s=ei[e], d=ei[NEDGES+e];
    int p=rp[d]+atomicAdd(&fill[d],1);
    ep[p]=make_int2(s, __float_as_int(dis[s]));
  }
}

__global__ void k_fill_comm(const int* __restrict__ comm, const int* __restrict__ crow, int* __restrict__ cfill,
                            int* __restrict__ cnode){
  int i=blockIdx.x*blockDim.x+threadIdx.x;
  if(i<NNODES){
    int c=comm[i];
    int p=crow[c]+atomicAdd(&cfill[c],1);
    cnode[p]=i;
  }
}

// ---------------- community mean (f32) ----------------
__global__ void k_comm_mean(const float* __restrict__ x, const int* __restrict__ crow,
                            const int* __restrict__ cnode, float* __restrict__ cmean){
  int c=blockIdx.x; int f=threadIdx.x; // 128 threads
  int a=crow[c], b=crow[c+1];
  float s=0.f;
  for(int j=a;j<b;j++){
    int nd=cnode[j];
    s += x[(size_t)nd*INCH + f];
  }
  float cnt=(float)(b-a);
  cmean[(size_t)c*INCH + f] = s / fmaxf(cnt,1.0f);
}

// ---------------- weight prep: split f32 W[K][N] into transposed bf16 hi/lo planes [N][K] ----------------
__global__ void k_wprep(const float* __restrict__ W_in, const float* __restrict__ W1, const float* __restrict__ W2,
                        ushort16* __restrict__ Wt0h, ushort16* __restrict__ Wt0l,
                        ushort16* __restrict__ Wt1h, ushort16* __restrict__ Wt1l,
                        ushort16* __restrict__ Wt2h, ushort16* __restrict__ Wt2l){
  int t = blockIdx.x*256 + threadIdx.x;
  float v; ushort16* ph; ushort16* pl; int off;
  if(t < 32768){            // W_in: [256][128] -> Wt0[n=128][k=256]
    int n=t>>8, k=t&255; v=W_in[k*128+n]; ph=Wt0h; pl=Wt0l; off=t;
  } else if(t < 49152){     // W1: [128][128] -> Wt1[128][128]
    int u=t-32768; int n=u>>7, k=u&127; v=W1[k*128+n]; ph=Wt1h; pl=Wt1l; off=u;
  } else if(t < 55296){     // W2: [128][40] -> Wt2[48][128], rows 40..47 zero
    int u=t-49152; int n=u>>7, k=u&127; v=(n<40)?W2[k*40+n]:0.f; ph=Wt2h; pl=Wt2l; off=u;
  } else return;
  unsigned short h=f2b(v); unsigned short lo=f2b(v-b2f(h));
  ph[off]=h; pl[off]=lo;
}

// ---------------- MFMA GEMM: out[M][128](bf16) = A[M][K] @ W + (bias, relu) ----------------
// CONCAT: A = [x | cmean[comm]] f32, K=256.  else: A = bf16 [M][K=128].
// Weights via Wt hi/lo planes [128][K] bf16 (transposed). Split: acc += A*Whi + A*Wlo.
template<int K, bool CONCAT, bool BIAS, bool RELU>
__global__ __launch_bounds__(256) void k_mm128(const void* __restrict__ A0, const float* __restrict__ A1f,
                                               const int* __restrict__ comm,
                                               const ushort16* __restrict__ WtH, const ushort16* __restrict__ WtL,
                                               const float* __restrict__ bias,
                                               ushort16* __restrict__ out, int M){
  __shared__ __align__(16) ushort16 As[128*40];   // row stride 40 ushorts (80B): 2-way bank alias only
  __shared__ __align__(16) ushort16 Bh[128*40];
  __shared__ __align__(16) ushort16 Bl[128*40];
  int t=threadIdx.x;
  int m0=blockIdx.x*128;
  int lane=t&63, w=t>>6;
  int g=lane>>4, r15=lane&15;

  f32x4 acc0[8], acc1[8];
  #pragma unroll
  for(int i=0;i<8;i++){ acc0[i]=(f32x4){0,0,0,0}; acc1[i]=(f32x4){0,0,0,0}; }

  int ar = t>>1, ko = (t&1)*16;     // staging coords: row, k-offset(16 elems)

  for(int kc=0;kc<K;kc+=32){
    __syncthreads();
    // ---- stage A chunk: 128 x 32 bf16 ----
    {
      s16x8 q0, q1;
      int gr = m0 + ar;
      if(gr < M){
        if(CONCAT){
          const float* src = (kc<128) ? ((const float*)A0 + (size_t)gr*128 + kc + ko)
                                      : (A1f + (size_t)comm[gr]*128 + (kc-128) + ko);
          float4 p0=ld4(src), p1=ld4(src+4), p2=ld4(src+8), p3=ld4(src+12);
          q0[0]=(short)f2b(p0.x); q0[1]=(short)f2b(p0.y); q0[2]=(short)f2b(p0.z); q0[3]=(short)f2b(p0.w);
          q0[4]=(short)f2b(p1.x); q0[5]=(short)f2b(p1.y); q0[6]=(short)f2b(p1.z); q0[7]=(short)f2b(p1.w);
          q1[0]=(short)f2b(p2.x); q1[1]=(short)f2b(p2.y); q1[2]=(short)f2b(p2.z); q1[3]=(short)f2b(p2.w);
          q1[4]=(short)f2b(p3.x); q1[5]=(short)f2b(p3.y); q1[6]=(short)f2b(p3.z); q1[7]=(short)f2b(p3.w);
        } else {
          const ushort16* srcu = (const ushort16*)A0 + (size_t)gr*K + kc + ko;
          q0 = *(const s16x8*)srcu;
          q1 = *(const s16x8*)(srcu+8);
        }
      } else {
        q0=(s16x8){0,0,0,0,0,0,0,0}; q1=q0;
      }
      ushort16* dst=&As[ar*40+ko];
      *(s16x8*)dst=q0; *(s16x8*)(dst+8)=q1;
    }
    // ---- stage B chunk: hi & lo planes, 128 x 32 bf16 each ----
    {
      const ushort16* sh=&WtH[(size_t)ar*K + kc + ko];
      s16x8 b0=*(const s16x8*)sh, b1=*(const s16x8*)(sh+8);
      ushort16* dh=&Bh[ar*40+ko];
      *(s16x8*)dh=b0; *(s16x8*)(dh+8)=b1;
      const ushort16* sl=&WtL[(size_t)ar*K + kc + ko];
      s16x8 c0=*(const s16x8*)sl, c1=*(const s16x8*)(sl+8);
      ushort16* dl=&Bl[ar*40+ko];
      *(s16x8*)dl=c0; *(s16x8*)(dl+8)=c1;
    }
    __syncthreads();
    // ---- MFMA: wave w owns rows [w*32, w*32+32) ----
    s16x8 a0 = *(const s16x8*)&As[(w*32      + r15)*40 + g*8];
    s16x8 a1 = *(const s16x8*)&As[(w*32 + 16 + r15)*40 + g*8];
    #pragma unroll
    for(int tn=0;tn<8;tn++){
      s16x8 bh = *(const s16x8*)&Bh[(tn*16 + r15)*40 + g*8];
      s16x8 bl = *(const s16x8*)&Bl[(tn*16 + r15)*40 + g*8];
      acc0[tn] = __builtin_amdgcn_mfma_f32_16x16x32_bf16(a0, bh, acc0[tn], 0,0,0);
      acc0[tn] = __builtin_amdgcn_mfma_f32_16x16x32_bf16(a0, bl, acc0[tn], 0,0,0);
      acc1[tn] = __builtin_amdgcn_mfma_f32_16x16x32_bf16(a1, bh, acc1[tn], 0,0,0);
      acc1[tn] = __builtin_amdgcn_mfma_f32_16x16x32_bf16(a1, bl, acc1[tn], 0,0,0);
    }
  }

  // ---- epilogue: D[row=(g*4+rr)][col=r15] per 16x16 tile ----
  #pragma unroll
  for(int tn=0;tn<8;tn++){
    int col = tn*16 + r15;
    float bv = BIAS ? bias[col] : 0.f;
    #pragma unroll
    for(int rr=0;rr<4;rr++){
      int row0 = m0 + w*32 + g*4 + rr;
      if(row0 < M){
        float v = acc0[tn][rr] + bv;
        if(RELU) v = fmaxf(v, 0.f);
        out[(size_t)row0*128 + col] = f2b(v);
      }
      int row1 = m0 + w*32 + 16 + g*4 + rr;
      if(row1 < M){
        float v = acc1[tn][rr] + bv;
        if(RELU) v = fmaxf(v, 0.f);
        out[(size_t)row1*128 + col] = f2b(v);
      }
    }
  }
}

// ---------------- MFMA GEMM: hw2[M][40](bf16) = h1[M][128](bf16) @ W2 ----------------
__global__ __launch_bounds__(256) void k_mm40(const ushort16* __restrict__ A0,
                                              const ushort16* __restrict__ WtH, const ushort16* __restrict__ WtL,
                                              ushort16* __restrict__ out, int M){
  __shared__ __align__(16) ushort16 As[128*40];
  __shared__ __align__(16) ushort16 Bh[48*40];
  __shared__ __align__(16) ushort16 Bl[48*40];
  int t=threadIdx.x;
  int m0=blockIdx.x*128;
  int lane=t&63, w=t>>6;
  int g=lane>>4, r15=lane&15;

  f32x4 acc0[3], acc1[3];
  #pragma unroll
  for(int i=0;i<3;i++){ acc0[i]=(f32x4){0,0,0,0}; acc1[i]=(f32x4){0,0,0,0}; }

  int ar=t>>1, ko=(t&1)*16;

  for(int kc=0;kc<128;kc+=32){
    __syncthreads();
    {
      s16x8 q0,q1;
      int gr=m0+ar;
      if(gr<M){
        const ushort16* srcu = A0 + (size_t)gr*128 + kc + ko;
        q0=*(const s16x8*)srcu; q1=*(const s16x8*)(srcu+8);
      } else { q0=(s16x8){0,0,0,0,0,0,0,0}; q1=q0; }
      ushort16* dst=&As[ar*40+ko];
      *(s16x8*)dst=q0; *(s16x8*)(dst+8)=q1;
    }
    if(t<96){
      int n=t>>1, k2=(t&1)*16;
      const ushort16* sh=&WtH[(size_t)n*128 + kc + k2];
      s16x8 b0=*(const s16x8*)sh, b1=*(const s16x8*)(sh+8);
      ushort16* dh=&Bh[n*40+k2];
      *(s16x8*)dh=b0; *(s16x8*)(dh+8)=b1;
    } else if(t<192){
      int u=t-96; int n=u>>1, k2=(u&1)*16;
      const ushort16* sl=&WtL[(size_t)n*128 + kc + k2];
      s16x8 c0=*(const s16x8*)sl, c1=*(const s16x8*)(sl+8);
      ushort16* dl=&Bl[n*40+k2];
      *(s16x8*)dl=c0; *(s16x8*)(dl+8)=c1;
    }
    __syncthreads();
    s16x8 a0=*(const s16x8*)&As[(w*32      + r15)*40 + g*8];
    s16x8 a1=*(const s16x8*)&As[(w*32 + 16 + r15)*40 + g*8];
    #pragma unroll
    for(int tn=0;tn<3;tn++){
      s16x8 bh=*(const s16x8*)&Bh[(tn*16 + r15)*40 + g*8];
      s16x8 bl=*(const s16x8*)&Bl[(tn*16 + r15)*40 + g*8];
      acc0[tn]=__builtin_amdgcn_mfma_f32_16x16x32_bf16(a0,bh,acc0[tn],0,0,0);
      acc0[tn]=__builtin_amdgcn_mfma_f32_16x16x32_bf16(a0,bl,acc0[tn],0,0,0);
      acc1[tn]=__builtin_amdgcn_mfma_f32_16x16x32_bf16(a1,bh,acc1[tn],0,0,0);
      acc1[tn]=__builtin_amdgcn_mfma_f32_16x16x32_bf16(a1,bl,acc1[tn],0,0,0);
    }
  }
  #pragma unroll
  for(int tn=0;tn<3;tn++){
    int col=tn*16+r15;
    if(col<NCLS){
      #pragma unroll
      for(int rr=0;rr<4;rr++){
        int row0=m0+w*32+g*4+rr;
        if(row0<M) out[(size_t)row0*NCLS+col]=f2b(acc0[tn][rr]);
        int row1=m0+w*32+16+g*4+rr;
        if(row1<M) out[(size_t)row1*NCLS+col]=f2b(acc1[tn][rr]);
      }
    }
  }
}

// ---------------- aggregation layer1 (bf16 gather, 128 feats): h1 = relu(agg + hw*dinv + b1) ----------------
__global__ __launch_bounds__(64) void k_agg_h(const uint32* __restrict__ hwu, const int* __restrict__ rp,
                                              const int2* __restrict__ ep,
                                              const float* __restrict__ dis, const float* __restrict__ dinv,
                                              const float* __restrict__ bias, uint32* __restrict__ h1u){
  int i=blockIdx.x; int l=threadIdx.x;
  int e0=rp[i], e1=rp[i+1];
  float di=dis[i];
  float ax=0.f, ay=0.f;
  for(int e=e0;e<e1;e++){
    int2 rec=ep[e];
    float nr=di*__int_as_float(rec.y);
    uint32 u=hwu[(size_t)rec.x*64 + l];
    float vx=__int_as_float((int)(u<<16));
    float vy=__int_as_float((int)(u&0xffff0000u));
    ax=fmaf(vx,nr,ax); ay=fmaf(vy,nr,ay);
  }
  uint32 su=hwu[(size_t)i*64+l];
  float sx=__int_as_float((int)(su<<16));
  float sy=__int_as_float((int)(su&0xffff0000u));
  float dv=dinv[i];
  float2 bb=*reinterpret_cast<const float2*>(&bias[2*l]);
  float ox=fmaxf(fmaf(sx,dv,ax)+bb.x,0.f);
  float oy=fmaxf(fmaf(sy,dv,ay)+bb.y,0.f);
  h1u[(size_t)i*64+l]=((uint32)f2b(oy)<<16)|(uint32)f2b(ox);
}

// ---------------- aggregation layer2 (bf16 gather, 40 feats): out = agg + hw2*dinv + b2 (f32 out) ----------------
__global__ __launch_bounds__(64) void k_agg_out(const ushort16* __restrict__ hw2u, const int* __restrict__ rp,
                                                const int2* __restrict__ ep,
                                                const float* __restrict__ dis, const float* __restrict__ dinv,
                                                const float* __restrict__ bias, float* __restrict__ out){
  int i=blockIdx.x; int l=threadIdx.x;
  if(l>=NCLS) return;
  int e0=rp[i], e1=rp[i+1];
  float di=dis[i];
  float a=0.f;
  for(int e=e0;e<e1;e++){
    int2 rec=ep[e];
    float nr=di*__int_as_float(rec.y);
    a=fmaf(b2f(hw2u[(size_t)rec.x*NCLS+l]),nr,a);
  }
  out[(size_t)i*NCLS+l]= a + b2f(hw2u[(size_t)i*NCLS+l])*dinv[i] + bias[l];
}

// ---------------- launcher ----------------
extern "C" void kernel_launch(void* const* d_in, const int* in_sizes, int n_in,
                              void* d_out, int out_size, void* d_ws, size_t ws_size,
                              hipStream_t stream) {
  const float* x    = (const float*)d_in[0];
  const int*   ei   = (const int*)  d_in[1];
  const int*   comm = (const int*)  d_in[2];
  const float* W_in = (const float*)d_in[3];
  const float* b_in = (const float*)d_in[4];
  const float* W1   = (const float*)d_in[5];
  const float* b1   = (const float*)d_in[6];
  const float* W2   = (const float*)d_in[7];
  const float* b2   = (const float*)d_in[8];
  float* out = (float*)d_out;

  char* base=(char*)d_ws; size_t off=0;
  auto alloc=[&](size_t bytes)->void*{ void* p=base+off; off=(off+bytes+255)&~(size_t)255; return p; };

  // zero zone (single contiguous memset): deg, fill, ccnt, cfill
  int* zz    =(int*)alloc((size_t)(2*NNODES+2*NCOMM_)*4);
  int* deg_i = zz;
  int* fill  = zz + NNODES;
  int* ccnt  = zz + 2*NNODES;
  int* cfill = zz + 2*NNODES + NCOMM_;
  int* rp    =(int*)alloc((size_t)(NNODES+1)*4);
  int* crow  =(int*)alloc((size_t)(NCOMM_+1)*4);
  int* partA =(int*)alloc(260*4);
  int* partB =(int*)alloc(16*4);
  int2* ep   =(int2*)alloc((size_t)NEDGES*8);
  int* cnode =(int*)alloc((size_t)NNODES*4);
  float* dis =(float*)alloc((size_t)NNODES*4);
  float* dinv=(float*)alloc((size_t)NNODES*4);
  float* cmean=(float*)alloc((size_t)NCOMM_*INCH*4);
  ushort16* h0 =(ushort16*)alloc((size_t)NNODES*HID*2);   // bf16; reused as h1
  ushort16* hw =(ushort16*)alloc((size_t)NNODES*HID*2);   // bf16; reused as hw2
  ushort16* Wt0h=(ushort16*)alloc(32768*2);
  ushort16* Wt0l=(ushort16*)alloc(32768*2);
  ushort16* Wt1h=(ushort16*)alloc(16384*2);
  ushort16* Wt1l=(ushort16*)alloc(16384*2);
  ushort16* Wt2h=(ushort16*)alloc(6144*2);
  ushort16* Wt2l=(ushort16*)alloc(6144*2);

  hipMemsetAsync(zz, 0, (size_t)(2*NNODES+2*NCOMM_)*4, stream);

  int gE=(NEDGES+255)/256, gN=(NNODES+255)/256;
  k_count<<<gE,256,0,stream>>>(ei, deg_i, comm, ccnt);

  int PA=(NNODES+1023)/1024;   // 98
  k_scan1<<<PA,256,0,stream>>>(deg_i, NNODES, partA);
  k_scan2<<<1,256,0,stream>>>(partA, PA);
  k_scan3<<<PA,256,0,stream>>>(deg_i, NNODES, partA, PA, rp);

  int PB=(NCOMM_+1023)/1024;   // 1
  k_scan1<<<PB,256,0,stream>>>(ccnt, NCOMM_, partB);
  k_scan2<<<1,256,0,stream>>>(partB, PB);
  k_scan3<<<PB,256,0,stream>>>(ccnt, NCOMM_, partB, PB, crow);

  k_nodeprep<<<gN,256,0,stream>>>(deg_i, dis, dinv);
  k_fill_edges<<<gE,256,0,stream>>>(ei, rp, fill, dis, ep);
  k_fill_comm<<<gN,256,0,stream>>>(comm, crow, cfill, cnode);
  k_comm_mean<<<NCOMM_,128,0,stream>>>(x, crow, cnode, cmean);
  k_wprep<<<216,256,0,stream>>>(W_in, W1, W2, Wt0h, Wt0l, Wt1h, Wt1l, Wt2h, Wt2l);

  int gM=(NNODES+127)/128;
  // h0 = relu([x | cmean[comm]] @ W_in + b_in)   (bf16 out)
  k_mm128<256,true,true,true><<<gM,256,0,stream>>>(x, cmean, comm, Wt0h, Wt0l, b_in, h0, NNODES);
  // hw = h0 @ W1  (bf16 out)
  k_mm128<128,false,false,false><<<gM,256,0,stream>>>(h0, nullptr, nullptr, Wt1h, Wt1l, nullptr, hw, NNODES);
  // h1 (into h0 buffer) = relu(agg(hw) + hw*dinv + b1)
  k_agg_h<<<NNODES,64,0,stream>>>((const uint32*)hw, rp, ep, dis, dinv, b1, (uint32*)h0);
  // hw2 (into hw buffer) = h1 @ W2
  k_mm40<<<gM,256,0,stream>>>(h0, Wt2h, Wt2l, hw, NNODES);
  // out = agg(hw2) + hw2*dinv + b2
  k_agg_out<<<NNODES,64,0,stream>>>(hw, rp, ep, dis, dinv, b2, out);
}

// Round 5
// 534.987 us; speedup vs baseline: 1.4114x; 1.1404x over previous
//
#include <hip/hip_runtime.h>
#include <cstdint>
#include <cstddef>

#define NNODES 100000
#define NEDGES 1600000
#define INCH   128
#define HID    128
#define NCLS   40
#define NCOMM_ 1000

typedef unsigned int uint32;
typedef unsigned short ushort16;
typedef short s16x8 __attribute__((ext_vector_type(8)));
typedef float f32x4 __attribute__((ext_vector_type(4)));

static __device__ __forceinline__ float4 ld4(const float* p){ return *reinterpret_cast<const float4*>(p); }

// f32 -> bf16 (RTN-even) and back, via bit ops
static __device__ __forceinline__ unsigned short f2b(float f){
  union{float f; uint32 u;} v; v.f=f;
  uint32 r = v.u + 0x7fffu + ((v.u>>16)&1u);
  return (unsigned short)(r>>16);
}
static __device__ __forceinline__ float b2f(unsigned short h){
  union{uint32 u; float f;} v; v.u = ((uint32)h)<<16; return v.f;
}
static __device__ __forceinline__ float lo16f(uint32 u){ return __int_as_float((int)(u<<16)); }
static __device__ __forceinline__ float hi16f(uint32 u){ return __int_as_float((int)(u&0xffff0000u)); }

static __device__ __forceinline__ void acc8(float* a, uint4 v, float nr){
  a[0]=fmaf(lo16f(v.x),nr,a[0]); a[1]=fmaf(hi16f(v.x),nr,a[1]);
  a[2]=fmaf(lo16f(v.y),nr,a[2]); a[3]=fmaf(hi16f(v.y),nr,a[3]);
  a[4]=fmaf(lo16f(v.z),nr,a[4]); a[5]=fmaf(hi16f(v.z),nr,a[5]);
  a[6]=fmaf(lo16f(v.w),nr,a[6]); a[7]=fmaf(hi16f(v.w),nr,a[7]);
}
static __device__ __forceinline__ void acc4(float* a, uint2 v, float nr){
  a[0]=fmaf(lo16f(v.x),nr,a[0]); a[1]=fmaf(hi16f(v.x),nr,a[1]);
  a[2]=fmaf(lo16f(v.y),nr,a[2]); a[3]=fmaf(hi16f(v.y),nr,a[3]);
}

// ---------------- counting (degrees by dst, community sizes) ----------------
__global__ void k_count(const int* __restrict__ ei, int* __restrict__ deg,
                        const int* __restrict__ comm, int* __restrict__ ccnt){
  int idx = blockIdx.x*blockDim.x + threadIdx.x;
  if (idx < NEDGES) atomicAdd(&deg[ei[NEDGES + idx]], 1);
  if (idx < NNODES) atomicAdd(&ccnt[comm[idx]], 1);
}

// ---------------- generic 3-phase exclusive scan (int) ----------------
__global__ void k_scan1(const int* __restrict__ in, int n, int* __restrict__ part){
  int t=threadIdx.x, b=blockIdx.x;
  int base=b*1024+t*4, s=0;
  #pragma unroll
  for(int j=0;j<4;j++){ int i=base+j; if(i<n) s+=in[i]; }
  #pragma unroll
  for(int off=32;off>0;off>>=1) s+=__shfl_down(s,off,64);
  __shared__ int wm[4];
  if((t&63)==0) wm[t>>6]=s;
  __syncthreads();
  if(t==0) part[b]=wm[0]+wm[1]+wm[2]+wm[3];
}

__global__ void k_scan2(int* __restrict__ part, int P){
  __shared__ int sm[256];
  int t=threadIdx.x;
  int v=(t<P)?part[t]:0;
  sm[t]=v; __syncthreads();
  #pragma unroll
  for(int off=1;off<256;off<<=1){
    int u=(t>=off)?sm[t-off]:0;
    __syncthreads();
    sm[t]+=u;
    __syncthreads();
  }
  if(t<P) part[t]=(t==0)?0:sm[t-1];
  if(t==0) part[P]=sm[255];
}

__global__ void k_scan3(const int* __restrict__ in, int n, const int* __restrict__ part, int P,
                        int* __restrict__ out){
  int t=threadIdx.x,b=blockIdx.x;
  int base=b*1024+t*4;
  int v[4], ts=0;
  #pragma unroll
  for(int j=0;j<4;j++){ v[j]=(base+j<n)?in[base+j]:0; ts+=v[j]; }
  int lane=t&63, w=t>>6, sc=ts;
  #pragma unroll
  for(int off=1;off<64;off<<=1){ int u=__shfl_up(sc,off,64); if(lane>=off) sc+=u; }
  __shared__ int wm[4];
  if(lane==63) wm[w]=sc;
  __syncthreads();
  int woff=0;
  for(int i=0;i<w;i++) woff+=wm[i];
  int pos=part[b]+woff+sc-ts;
  #pragma unroll
  for(int j=0;j<4;j++){ if(base+j<n) out[base+j]=pos; pos+=v[j]; }
  if(b==0 && t==0) out[n]=part[P];
}

// ---------------- per-node norm factors ----------------
__global__ void k_nodeprep(const int* __restrict__ deg, float* __restrict__ dis, float* __restrict__ dinv){
  int i=blockIdx.x*blockDim.x+threadIdx.x;
  if(i<NNODES){ float d=(float)(deg[i]+1); dis[i]=rsqrtf(d); dinv[i]=1.0f/d; }
}

// ---------------- CSR fills: packed edge record {src, dis[src]} ----------------
__global__ void k_fill_edges(const int* __restrict__ ei, const int* __restrict__ rp, int* __restrict__ fill,
                             const float* __restrict__ dis, int2* __restrict__ ep){
  int e=blockIdx.x*blockDim.x+threadIdx.x;
  if(e<NEDGES){
    int s=ei[e], d=ei[NEDGES+e];
    int p=rp[d]+atomicAdd(&fill[d],1);
    ep[p]=make_int2(s, __float_as_int(dis[s]));
  }
}

__global__ void k_fill_comm(const int* __restrict__ comm, const int* __restrict__ crow, int* __restrict__ cfill,
                            int* __restrict__ cnode){
  int i=blockIdx.x*blockDim.x+threadIdx.x;
  if(i<NNODES){
    int c=comm[i];
    int p=crow[c]+atomicAdd(&cfill[c],1);
    cnode[p]=i;
  }
}

// ---------------- community mean (f32) ----------------
__global__ void k_comm_mean(const float* __restrict__ x, const int* __restrict__ crow,
                            const int* __restrict__ cnode, float* __restrict__ cmean){
  int c=blockIdx.x; int f=threadIdx.x; // 128 threads
  int a=crow[c], b=crow[c+1];
  float s=0.f;
  for(int j=a;j<b;j++){
    int nd=cnode[j];
    s += x[(size_t)nd*INCH + f];
  }
  float cnt=(float)(b-a);
  cmean[(size_t)c*INCH + f] = s / fmaxf(cnt,1.0f);
}

// ---------------- weight prep: split f32 W[K][N] into transposed bf16 hi/lo planes [N][K] ----------------
__global__ void k_wprep(const float* __restrict__ W_in, const float* __restrict__ W1, const float* __restrict__ W2,
                        ushort16* __restrict__ Wt0h, ushort16* __restrict__ Wt0l,
                        ushort16* __restrict__ Wt1h, ushort16* __restrict__ Wt1l,
                        ushort16* __restrict__ Wt2h, ushort16* __restrict__ Wt2l){
  int t = blockIdx.x*256 + threadIdx.x;
  float v; ushort16* ph; ushort16* pl; int off;
  if(t < 32768){            // W_in: [256][128] -> Wt0[n=128][k=256]
    int n=t>>8, k=t&255; v=W_in[k*128+n]; ph=Wt0h; pl=Wt0l; off=t;
  } else if(t < 49152){     // W1: [128][128] -> Wt1[128][128]
    int u=t-32768; int n=u>>7, k=u&127; v=W1[k*128+n]; ph=Wt1h; pl=Wt1l; off=u;
  } else if(t < 55296){     // W2: [128][40] -> Wt2[48][128], rows 40..47 zero
    int u=t-49152; int n=u>>7, k=u&127; v=(n<40)?W2[k*40+n]:0.f; ph=Wt2h; pl=Wt2l; off=u;
  } else return;
  unsigned short h=f2b(v); unsigned short lo=f2b(v-b2f(h));
  ph[off]=h; pl[off]=lo;
}

// ---------------- MFMA GEMM: out[M][128](bf16) = A[M][K] @ W + (bias, relu) ----------------
template<int K, bool CONCAT, bool BIAS, bool RELU>
__global__ __launch_bounds__(256) void k_mm128(const void* __restrict__ A0, const float* __restrict__ A1f,
                                               const int* __restrict__ comm,
                                               const ushort16* __restrict__ WtH, const ushort16* __restrict__ WtL,
                                               const float* __restrict__ bias,
                                               ushort16* __restrict__ out, int M){
  __shared__ __align__(16) ushort16 As[128*40];   // row stride 40 ushorts (80B): 2-way bank alias only
  __shared__ __align__(16) ushort16 Bh[128*40];
  __shared__ __align__(16) ushort16 Bl[128*40];
  int t=threadIdx.x;
  int m0=blockIdx.x*128;
  int lane=t&63, w=t>>6;
  int g=lane>>4, r15=lane&15;

  f32x4 acc0[8], acc1[8];
  #pragma unroll
  for(int i=0;i<8;i++){ acc0[i]=(f32x4){0,0,0,0}; acc1[i]=(f32x4){0,0,0,0}; }

  int ar = t>>1, ko = (t&1)*16;     // staging coords: row, k-offset(16 elems)

  for(int kc=0;kc<K;kc+=32){
    __syncthreads();
    // ---- stage A chunk: 128 x 32 bf16 ----
    {
      s16x8 q0, q1;
      int gr = m0 + ar;
      if(gr < M){
        if(CONCAT){
          const float* src = (kc<128) ? ((const float*)A0 + (size_t)gr*128 + kc + ko)
                                      : (A1f + (size_t)comm[gr]*128 + (kc-128) + ko);
          float4 p0=ld4(src), p1=ld4(src+4), p2=ld4(src+8), p3=ld4(src+12);
          q0[0]=(short)f2b(p0.x); q0[1]=(short)f2b(p0.y); q0[2]=(short)f2b(p0.z); q0[3]=(short)f2b(p0.w);
          q0[4]=(short)f2b(p1.x); q0[5]=(short)f2b(p1.y); q0[6]=(short)f2b(p1.z); q0[7]=(short)f2b(p1.w);
          q1[0]=(short)f2b(p2.x); q1[1]=(short)f2b(p2.y); q1[2]=(short)f2b(p2.z); q1[3]=(short)f2b(p2.w);
          q1[4]=(short)f2b(p3.x); q1[5]=(short)f2b(p3.y); q1[6]=(short)f2b(p3.z); q1[7]=(short)f2b(p3.w);
        } else {
          const ushort16* srcu = (const ushort16*)A0 + (size_t)gr*K + kc + ko;
          q0 = *(const s16x8*)srcu;
          q1 = *(const s16x8*)(srcu+8);
        }
      } else {
        q0=(s16x8){0,0,0,0,0,0,0,0}; q1=q0;
      }
      ushort16* dst=&As[ar*40+ko];
      *(s16x8*)dst=q0; *(s16x8*)(dst+8)=q1;
    }
    // ---- stage B chunk: hi & lo planes ----
    {
      const ushort16* sh=&WtH[(size_t)ar*K + kc + ko];
      s16x8 b0=*(const s16x8*)sh, b1=*(const s16x8*)(sh+8);
      ushort16* dh=&Bh[ar*40+ko];
      *(s16x8*)dh=b0; *(s16x8*)(dh+8)=b1;
      const ushort16* sl=&WtL[(size_t)ar*K + kc + ko];
      s16x8 c0=*(const s16x8*)sl, c1=*(const s16x8*)(sl+8);
      ushort16* dl=&Bl[ar*40+ko];
      *(s16x8*)dl=c0; *(s16x8*)(dl+8)=c1;
    }
    __syncthreads();
    s16x8 a0 = *(const s16x8*)&As[(w*32      + r15)*40 + g*8];
    s16x8 a1 = *(const s16x8*)&As[(w*32 + 16 + r15)*40 + g*8];
    #pragma unroll
    for(int tn=0;tn<8;tn++){
      s16x8 bh = *(const s16x8*)&Bh[(tn*16 + r15)*40 + g*8];
      s16x8 bl = *(const s16x8*)&Bl[(tn*16 + r15)*40 + g*8];
      acc0[tn] = __builtin_amdgcn_mfma_f32_16x16x32_bf16(a0, bh, acc0[tn], 0,0,0);
      acc0[tn] = __builtin_amdgcn_mfma_f32_16x16x32_bf16(a0, bl, acc0[tn], 0,0,0);
      acc1[tn] = __builtin_amdgcn_mfma_f32_16x16x32_bf16(a1, bh, acc1[tn], 0,0,0);
      acc1[tn] = __builtin_amdgcn_mfma_f32_16x16x32_bf16(a1, bl, acc1[tn], 0,0,0);
    }
  }

  #pragma unroll
  for(int tn=0;tn<8;tn++){
    int col = tn*16 + r15;
    float bv = BIAS ? bias[col] : 0.f;
    #pragma unroll
    for(int rr=0;rr<4;rr++){
      int row0 = m0 + w*32 + g*4 + rr;
      if(row0 < M){
        float v = acc0[tn][rr] + bv;
        if(RELU) v = fmaxf(v, 0.f);
        out[(size_t)row0*128 + col] = f2b(v);
      }
      int row1 = m0 + w*32 + 16 + g*4 + rr;
      if(row1 < M){
        float v = acc1[tn][rr] + bv;
        if(RELU) v = fmaxf(v, 0.f);
        out[(size_t)row1*128 + col] = f2b(v);
      }
    }
  }
}

// ---------------- MFMA GEMM: hw2[M][40](bf16) = h1[M][128](bf16) @ W2 ----------------
__global__ __launch_bounds__(256) void k_mm40(const ushort16* __restrict__ A0,
                                              const ushort16* __restrict__ WtH, const ushort16* __restrict__ WtL,
                                              ushort16* __restrict__ out, int M){
  __shared__ __align__(16) ushort16 As[128*40];
  __shared__ __align__(16) ushort16 Bh[48*40];
  __shared__ __align__(16) ushort16 Bl[48*40];
  int t=threadIdx.x;
  int m0=blockIdx.x*128;
  int lane=t&63, w=t>>6;
  int g=lane>>4, r15=lane&15;

  f32x4 acc0[3], acc1[3];
  #pragma unroll
  for(int i=0;i<3;i++){ acc0[i]=(f32x4){0,0,0,0}; acc1[i]=(f32x4){0,0,0,0}; }

  int ar=t>>1, ko=(t&1)*16;

  for(int kc=0;kc<128;kc+=32){
    __syncthreads();
    {
      s16x8 q0,q1;
      int gr=m0+ar;
      if(gr<M){
        const ushort16* srcu = A0 + (size_t)gr*128 + kc + ko;
        q0=*(const s16x8*)srcu; q1=*(const s16x8*)(srcu+8);
      } else { q0=(s16x8){0,0,0,0,0,0,0,0}; q1=q0; }
      ushort16* dst=&As[ar*40+ko];
      *(s16x8*)dst=q0; *(s16x8*)(dst+8)=q1;
    }
    if(t<96){
      int n=t>>1, k2=(t&1)*16;
      const ushort16* sh=&WtH[(size_t)n*128 + kc + k2];
      s16x8 b0=*(const s16x8*)sh, b1=*(const s16x8*)(sh+8);
      ushort16* dh=&Bh[n*40+k2];
      *(s16x8*)dh=b0; *(s16x8*)(dh+8)=b1;
    } else if(t<192){
      int u=t-96; int n=u>>1, k2=(u&1)*16;
      const ushort16* sl=&WtL[(size_t)n*128 + kc + k2];
      s16x8 c0=*(const s16x8*)sl, c1=*(const s16x8*)(sl+8);
      ushort16* dl=&Bl[n*40+k2];
      *(s16x8*)dl=c0; *(s16x8*)(dl+8)=c1;
    }
    __syncthreads();
    s16x8 a0=*(const s16x8*)&As[(w*32      + r15)*40 + g*8];
    s16x8 a1=*(const s16x8*)&As[(w*32 + 16 + r15)*40 + g*8];
    #pragma unroll
    for(int tn=0;tn<3;tn++){
      s16x8 bh=*(const s16x8*)&Bh[(tn*16 + r15)*40 + g*8];
      s16x8 bl=*(const s16x8*)&Bl[(tn*16 + r15)*40 + g*8];
      acc0[tn]=__builtin_amdgcn_mfma_f32_16x16x32_bf16(a0,bh,acc0[tn],0,0,0);
      acc0[tn]=__builtin_amdgcn_mfma_f32_16x16x32_bf16(a0,bl,acc0[tn],0,0,0);
      acc1[tn]=__builtin_amdgcn_mfma_f32_16x16x32_bf16(a1,bh,acc1[tn],0,0,0);
      acc1[tn]=__builtin_amdgcn_mfma_f32_16x16x32_bf16(a1,bl,acc1[tn],0,0,0);
    }
  }
  #pragma unroll
  for(int tn=0;tn<3;tn++){
    int col=tn*16+r15;
    if(col<NCLS){
      #pragma unroll
      for(int rr=0;rr<4;rr++){
        int row0=m0+w*32+g*4+rr;
        if(row0<M) out[(size_t)row0*NCLS+col]=f2b(acc0[tn][rr]);
        int row1=m0+w*32+16+g*4+rr;
        if(row1<M) out[(size_t)row1*NCLS+col]=f2b(acc1[tn][rr]);
      }
    }
  }
}

// ---------------- aggregation layer1: 4 waves/block (1 node each); 4 edge-groups x 16 lanes ----------------
// lane f (0..15) covers feats [8f, 8f+7] via one uint4 (16B). Row = 16 uint4. 8 gathers in flight/wave.
__global__ __launch_bounds__(256) void k_agg_h(const uint4* __restrict__ hwv, const int* __restrict__ rp,
                                               const int2* __restrict__ ep,
                                               const float* __restrict__ dis, const float* __restrict__ dinv,
                                               const float* __restrict__ bias, uint4* __restrict__ h1v){
  int w=threadIdx.x>>6;
  int i=blockIdx.x*4+w;
  if(i>=NNODES) return;
  int lane=threadIdx.x&63;
  int g=lane>>4, f=lane&15;
  int e0=rp[i], e1=rp[i+1];
  float di=dis[i];
  float a[8]={0,0,0,0,0,0,0,0};
  int e=e0+g;
  for(; e+4<e1; e+=8){
    int2 r0=ep[e], r1=ep[e+4];
    float n0=di*__int_as_float(r0.y), n1=di*__int_as_float(r1.y);
    uint4 v0=hwv[(size_t)r0.x*16+f];
    uint4 v1=hwv[(size_t)r1.x*16+f];
    acc8(a,v0,n0); acc8(a,v1,n1);
  }
  if(e<e1){
    int2 r0=ep[e];
    float n0=di*__int_as_float(r0.y);
    uint4 v0=hwv[(size_t)r0.x*16+f];
    acc8(a,v0,n0);
  }
  #pragma unroll
  for(int k=0;k<8;k++){
    a[k]+=__shfl_xor(a[k],16);
    a[k]+=__shfl_xor(a[k],32);
  }
  if(g==0){
    uint4 sv=hwv[(size_t)i*16+f];
    float dv=dinv[i];
    float4 bA=*reinterpret_cast<const float4*>(&bias[8*f]);
    float4 bB=*reinterpret_cast<const float4*>(&bias[8*f+4]);
    float o0=fmaxf(fmaf(lo16f(sv.x),dv,a[0])+bA.x,0.f);
    float o1=fmaxf(fmaf(hi16f(sv.x),dv,a[1])+bA.y,0.f);
    float o2=fmaxf(fmaf(lo16f(sv.y),dv,a[2])+bA.z,0.f);
    float o3=fmaxf(fmaf(hi16f(sv.y),dv,a[3])+bA.w,0.f);
    float o4=fmaxf(fmaf(lo16f(sv.z),dv,a[4])+bB.x,0.f);
    float o5=fmaxf(fmaf(hi16f(sv.z),dv,a[5])+bB.y,0.f);
    float o6=fmaxf(fmaf(lo16f(sv.w),dv,a[6])+bB.z,0.f);
    float o7=fmaxf(fmaf(hi16f(sv.w),dv,a[7])+bB.w,0.f);
    uint4 o;
    o.x=((uint32)f2b(o1)<<16)|(uint32)f2b(o0);
    o.y=((uint32)f2b(o3)<<16)|(uint32)f2b(o2);
    o.z=((uint32)f2b(o5)<<16)|(uint32)f2b(o4);
    o.w=((uint32)f2b(o7)<<16)|(uint32)f2b(o6);
    h1v[(size_t)i*16+f]=o;
  }
}

// ---------------- aggregation layer2: 4 waves/block; 4 edge-groups x 16 lanes (10 active) ----------------
// lane f (0..9) covers feats [4f, 4f+3] via one uint2 (8B). Row = 10 uint2. f32 output.
__global__ __launch_bounds__(256) void k_agg_out(const uint2* __restrict__ hv, const int* __restrict__ rp,
                                                 const int2* __restrict__ ep,
                                                 const float* __restrict__ dis, const float* __restrict__ dinv,
                                                 const float* __restrict__ bias, float* __restrict__ out){
  int w=threadIdx.x>>6;
  int i=blockIdx.x*4+w;
  if(i>=NNODES) return;
  int lane=threadIdx.x&63;
  int g=lane>>4, f=lane&15;
  bool act=(f<10);
  int e0=rp[i], e1=rp[i+1];
  float di=dis[i];
  float a[4]={0,0,0,0};
  int e=e0+g;
  for(; e+4<e1; e+=8){
    int2 r0=ep[e], r1=ep[e+4];
    float n0=di*__int_as_float(r0.y), n1=di*__int_as_float(r1.y);
    if(act){
      uint2 v0=hv[(size_t)r0.x*10+f];
      uint2 v1=hv[(size_t)r1.x*10+f];
      acc4(a,v0,n0); acc4(a,v1,n1);
    }
  }
  if(e<e1){
    int2 r0=ep[e];
    float n0=di*__int_as_float(r0.y);
    if(act){
      uint2 v0=hv[(size_t)r0.x*10+f];
      acc4(a,v0,n0);
    }
  }
  #pragma unroll
  for(int k=0;k<4;k++){
    a[k]+=__shfl_xor(a[k],16);
    a[k]+=__shfl_xor(a[k],32);
  }
  if(g==0 && act){
    uint2 sv=hv[(size_t)i*10+f];
    float dv=dinv[i];
    float4 b=*reinterpret_cast<const float4*>(&bias[4*f]);
    float4 o;
    o.x=fmaf(lo16f(sv.x),dv,a[0])+b.x;
    o.y=fmaf(hi16f(sv.x),dv,a[1])+b.y;
    o.z=fmaf(lo16f(sv.y),dv,a[2])+b.z;
    o.w=fmaf(hi16f(sv.y),dv,a[3])+b.w;
    *reinterpret_cast<float4*>(&out[(size_t)i*40+4*f])=o;
  }
}

// ---------------- launcher ----------------
extern "C" void kernel_launch(void* const* d_in, const int* in_sizes, int n_in,
                              void* d_out, int out_size, void* d_ws, size_t ws_size,
                              hipStream_t stream) {
  const float* x    = (const float*)d_in[0];
  const int*   ei   = (const int*)  d_in[1];
  const int*   comm = (const int*)  d_in[2];
  const float* W_in = (const float*)d_in[3];
  const float* b_in = (const float*)d_in[4];
  const float* W1   = (const float*)d_in[5];
  const float* b1   = (const float*)d_in[6];
  const float* W2   = (const float*)d_in[7];
  const float* b2   = (const float*)d_in[8];
  float* out = (float*)d_out;

  char* base=(char*)d_ws; size_t off=0;
  auto alloc=[&](size_t bytes)->void*{ void* p=base+off; off=(off+bytes+255)&~(size_t)255; return p; };

  // zero zone (single contiguous memset): deg, fill, ccnt, cfill
  int* zz    =(int*)alloc((size_t)(2*NNODES+2*NCOMM_)*4);
  int* deg_i = zz;
  int* fill  = zz + NNODES;
  int* ccnt  = zz + 2*NNODES;
  int* cfill = zz + 2*NNODES + NCOMM_;
  int* rp    =(int*)alloc((size_t)(NNODES+1)*4);
  int* crow  =(int*)alloc((size_t)(NCOMM_+1)*4);
  int* partA =(int*)alloc(260*4);
  int* partB =(int*)alloc(16*4);
  int2* ep   =(int2*)alloc((size_t)NEDGES*8);
  int* cnode =(int*)alloc((size_t)NNODES*4);
  float* dis =(float*)alloc((size_t)NNODES*4);
  float* dinv=(float*)alloc((size_t)NNODES*4);
  float* cmean=(float*)alloc((size_t)NCOMM_*INCH*4);
  ushort16* h0 =(ushort16*)alloc((size_t)NNODES*HID*2);   // bf16; reused as h1
  ushort16* hw =(ushort16*)alloc((size_t)NNODES*HID*2);   // bf16; reused as hw2
  ushort16* Wt0h=(ushort16*)alloc(32768*2);
  ushort16* Wt0l=(ushort16*)alloc(32768*2);
  ushort16* Wt1h=(ushort16*)alloc(16384*2);
  ushort16* Wt1l=(ushort16*)alloc(16384*2);
  ushort16* Wt2h=(ushort16*)alloc(6144*2);
  ushort16* Wt2l=(ushort16*)alloc(6144*2);

  hipMemsetAsync(zz, 0, (size_t)(2*NNODES+2*NCOMM_)*4, stream);

  int gE=(NEDGES+255)/256, gN=(NNODES+255)/256;
  k_count<<<gE,256,0,stream>>>(ei, deg_i, comm, ccnt);

  int PA=(NNODES+1023)/1024;   // 98
  k_scan1<<<PA,256,0,stream>>>(deg_i, NNODES, partA);
  k_scan2<<<1,256,0,stream>>>(partA, PA);
  k_scan3<<<PA,256,0,stream>>>(deg_i, NNODES, partA, PA, rp);

  int PB=(NCOMM_+1023)/1024;   // 1
  k_scan1<<<PB,256,0,stream>>>(ccnt, NCOMM_, partB);
  k_scan2<<<1,256,0,stream>>>(partB, PB);
  k_scan3<<<PB,256,0,stream>>>(ccnt, NCOMM_, partB, PB, crow);

  k_nodeprep<<<gN,256,0,stream>>>(deg_i, dis, dinv);
  k_fill_edges<<<gE,256,0,stream>>>(ei, rp, fill, dis, ep);
  k_fill_comm<<<gN,256,0,stream>>>(comm, crow, cfill, cnode);
  k_comm_mean<<<NCOMM_,128,0,stream>>>(x, crow, cnode, cmean);
  k_wprep<<<216,256,0,stream>>>(W_in, W1, W2, Wt0h, Wt0l, Wt1h, Wt1l, Wt2h, Wt2l);

  int gM=(NNODES+127)/128;
  // h0 = relu([x | cmean[comm]] @ W_in + b_in)   (bf16 out)
  k_mm128<256,true,true,true><<<gM,256,0,stream>>>(x, cmean, comm, Wt0h, Wt0l, b_in, h0, NNODES);
  // hw = h0 @ W1  (bf16 out)
  k_mm128<128,false,false,false><<<gM,256,0,stream>>>(h0, nullptr, nullptr, Wt1h, Wt1l, nullptr, hw, NNODES);
  // h1 (into h0 buffer) = relu(agg(hw) + hw*dinv + b1)
  int gA=(NNODES+3)/4;
  k_agg_h<<<gA,256,0,stream>>>((const uint4*)hw, rp, ep, dis, dinv, b1, (uint4*)h0);
  // hw2 (into hw buffer) = h1 @ W2
  k_mm40<<<gM,256,0,stream>>>(h0, Wt2h, Wt2l, hw, NNODES);
  // out = agg(hw2) + hw2*dinv + b2
  k_agg_out<<<gA,256,0,stream>>>((const uint2*)hw, rp, ep, dis, dinv, b2, out);
}